// Round 1
// baseline (17.672 us; speedup 1.0000x reference)
//
#include <hip/hip_runtime.h>
#include <math.h>

// Problem constants (fixed by the reference): B=2, N=64, CI=CO=32
#define NZ 2
#define NN 64
#define NCI 32
#define NCO 32

// ws layout (floats):
//   partials [NZ][32][7][32] : offset 0      size 14336
//   QA       [NZ][3][32]     : offset 14336  size 192
//   QB       [NZ][3][32]     : offset 14528  size 192
//   gamma    [NZ][32]        : offset 14720  size 64
#define WS_PART 0
#define WS_QA   14336
#define WS_QB   14528
#define WS_GAM  14720

// ---------------------------------------------------------------------------
// Kernel 1: per-z feature reductions.
//   ft[z,j]   = sum_{c,d} f[z,c,d,j]
//   Gs[z,x,j] = sum_{c,d} geom[z,c,x] * f[z,c,d,j]
//   Gd[z,x,j] = sum_{c,d} geom[z,d,x] * f[z,c,d,j]
// 64 blocks (32 slices per z), 256 threads = 8 groups x 32 lanes (lane = j).
// Each group covers 16 (c,d) pairs; block writes one partial slice [7][32].
// ---------------------------------------------------------------------------
__global__ __launch_bounds__(256) void k_reduce(const float* __restrict__ feat,
                                                const float* __restrict__ geom,
                                                float* __restrict__ part) {
    const int bid = blockIdx.x;
    const int z = bid >> 5;        // 0..1
    const int s = bid & 31;        // slice 0..31
    const int tid = threadIdx.x;
    const int j = tid & 31;
    const int grp = tid >> 5;      // 0..7

    __shared__ float gsh[NN * 3];
    __shared__ float red[8][7][32];

    if (tid < NN * 3) gsh[tid] = geom[z * NN * 3 + tid];
    __syncthreads();

    float ft = 0.f;
    float a0 = 0.f, a1 = 0.f, a2 = 0.f;   // Gs partials (x=0..2)
    float b0 = 0.f, b1 = 0.f, b2 = 0.f;   // Gd partials

    const float* fz = feat + (size_t)z * NN * NN * NCI;
    const int p0 = s * 128 + grp * 16;
    #pragma unroll 4
    for (int t = 0; t < 16; ++t) {
        const int p = p0 + t;
        const float f = fz[p * NCI + j];
        const int c = p >> 6;
        const int d = p & 63;
        const float gc0 = gsh[c * 3 + 0], gc1 = gsh[c * 3 + 1], gc2 = gsh[c * 3 + 2];
        const float gd0 = gsh[d * 3 + 0], gd1 = gsh[d * 3 + 1], gd2 = gsh[d * 3 + 2];
        ft += f;
        a0 = fmaf(gc0, f, a0); a1 = fmaf(gc1, f, a1); a2 = fmaf(gc2, f, a2);
        b0 = fmaf(gd0, f, b0); b1 = fmaf(gd1, f, b1); b2 = fmaf(gd2, f, b2);
    }

    red[grp][0][j] = ft;
    red[grp][1][j] = a0; red[grp][2][j] = a1; red[grp][3][j] = a2;
    red[grp][4][j] = b0; red[grp][5][j] = b1; red[grp][6][j] = b2;
    __syncthreads();

    if (tid < 7 * 32) {
        const int q = tid >> 5, jj = tid & 31;
        float sum = 0.f;
        #pragma unroll
        for (int g = 0; g < 8; ++g) sum += red[g][q][jj];
        part[((z * 32 + s) * 7 + q) * 32 + jj] = sum;
    }
}

// ---------------------------------------------------------------------------
// Kernel 2: finish reduction, fold W into per-z coefficient tables.
//   Qm[z,x,i]  = sum_j Wm[x,i,j] * ft[z,j]              (m = 1..6, 0-indexed)
//   QA[z,x,i]  = scale * (Q1 + Q2 + Q3)                  (multiplies -g_a[x])
//   QB[z,x,i]  = scale * (Q1 - Q4 - Q5)                  (multiplies +g_b[x])
//   gamma[z,i] = scale * sum_{x,j} [(W2+W4-W6)*Gs + (W3+W5+W6)*Gd]
// 2 blocks (one per z), 128 threads (96 active: x = tid/32, i = tid%32).
// ---------------------------------------------------------------------------
__global__ __launch_bounds__(128) void k_coeff(const float* __restrict__ part,
                                               const float* __restrict__ W,
                                               const int* __restrict__ nnp,
                                               float* __restrict__ QA,
                                               float* __restrict__ QB,
                                               float* __restrict__ gam) {
    const int z = blockIdx.x;
    const int tid = threadIdx.x;

    __shared__ float acc[7][32];    // ft, Gs[0..2], Gd[0..2]
    __shared__ float gred[3][32];

    // Phase A: reduce the 32 partial slices.
    for (int idx = tid; idx < 7 * 32; idx += 128) {
        const int q = idx >> 5, j = idx & 31;
        float sum = 0.f;
        for (int s = 0; s < 32; ++s)
            sum += part[((z * 32 + s) * 7 + q) * 32 + j];
        acc[q][j] = sum;
    }
    __syncthreads();

    // n_norm: Python scalar -> 1-elem array; hedge int32 vs float32 bits.
    const int v = *nnp;
    const float nn = (v > 0 && v < (1 << 23)) ? (float)v : __int_as_float(v);
    const float scale = 1.0f / sqrtf(6.0f * nn * nn);

    if (tid < 96) {
        const int x = tid >> 5;    // 0..2
        const int i = tid & 31;
        const float* Wp = W + x * 6 * NCO * NCI;  // W[x, m*1024 + i*32 + j]
        float q1 = 0.f, q23 = 0.f, q45 = 0.f, gp = 0.f;
        for (int j = 0; j < 32; ++j) {
            const float ftj = acc[0][j];
            const float gsj = acc[1 + x][j];
            const float gdj = acc[4 + x][j];
            const float w0 = Wp[0 * 1024 + i * 32 + j];
            const float w1 = Wp[1 * 1024 + i * 32 + j];
            const float w2 = Wp[2 * 1024 + i * 32 + j];
            const float w3 = Wp[3 * 1024 + i * 32 + j];
            const float w4 = Wp[4 * 1024 + i * 32 + j];
            const float w5 = Wp[5 * 1024 + i * 32 + j];
            q1  = fmaf(w0, ftj, q1);
            q23 = fmaf(w1 + w2, ftj, q23);
            q45 = fmaf(w3 + w4, ftj, q45);
            gp  = fmaf(w1 + w3 - w5, gsj, gp);
            gp  = fmaf(w2 + w4 + w5, gdj, gp);
        }
        QA[(z * 3 + x) * 32 + i] = scale * (q1 + q23);
        QB[(z * 3 + x) * 32 + i] = scale * (q1 - q45);
        gred[x][i] = gp;
    }
    __syncthreads();

    if (tid < 32) {
        gam[z * 32 + tid] = scale * (gred[0][tid] + gred[1][tid] + gred[2][tid]);
    }
}

// ---------------------------------------------------------------------------
// Kernel 3: out[z,a,b,i] = gamma[z,i] + sum_x (g_b[x]*QB[z,x,i] - g_a[x]*QA[z,x,i])
// Fully coalesced write (i innermost). Tables are L1/L2-resident.
// ---------------------------------------------------------------------------
__global__ __launch_bounds__(256) void k_out(const float* __restrict__ geom,
                                             const float* __restrict__ QA,
                                             const float* __restrict__ QB,
                                             const float* __restrict__ gam,
                                             float* __restrict__ out, int total) {
    const int idx = blockIdx.x * 256 + threadIdx.x;
    if (idx >= total) return;
    const int i = idx & 31;
    const int b = (idx >> 5) & 63;
    const int a = (idx >> 11) & 63;
    const int z = idx >> 17;

    const float* gz = geom + z * NN * 3;
    float r = gam[z * 32 + i];
    #pragma unroll
    for (int x = 0; x < 3; ++x) {
        r = fmaf(gz[b * 3 + x], QB[(z * 3 + x) * 32 + i], r);
        r = fmaf(-gz[a * 3 + x], QA[(z * 3 + x) * 32 + i], r);
    }
    out[idx] = r;
}

extern "C" void kernel_launch(void* const* d_in, const int* in_sizes, int n_in,
                              void* d_out, int out_size, void* d_ws, size_t ws_size,
                              hipStream_t stream) {
    const float* feat = (const float*)d_in[0];   // [2,64,64,32]
    const float* geom = (const float*)d_in[1];   // [2,64,3]
    const float* W    = (const float*)d_in[2];   // [3,6144]
    const int*   nnp  = (const int*)d_in[3];     // scalar n_norm

    float* ws   = (float*)d_ws;
    float* part = ws + WS_PART;
    float* QA   = ws + WS_QA;
    float* QB   = ws + WS_QB;
    float* gam  = ws + WS_GAM;
    float* out  = (float*)d_out;

    k_reduce<<<NZ * 32, 256, 0, stream>>>(feat, geom, part);
    k_coeff<<<NZ, 128, 0, stream>>>(part, W, nnp, QA, QB, gam);

    const int total = out_size;  // 2*64*64*32 = 262144
    k_out<<<(total + 255) / 256, 256, 0, stream>>>(geom, QA, QB, gam, out, total);
}

// Round 2
// 17.247 us; speedup vs baseline: 1.0247x; 1.0247x over previous
//
#include <hip/hip_runtime.h>
#include <math.h>

// Problem constants (fixed by the reference): B=2, N=64, CI=CO=32
#define NZ 2
#define NN 64
#define NCI 32
#define NCO 32

// ws layout (floats): partials [NZ][32][7][32]  (7168 floats per z)
#define PART_Z_STRIDE (32 * 7 * 32)

__device__ __forceinline__ void ld4(const float* __restrict__ p, float* d) {
    const float4 v = *(const float4*)p;
    d[0] = v.x; d[1] = v.y; d[2] = v.z; d[3] = v.w;
}

// ---------------------------------------------------------------------------
// Kernel 1: per-z feature reductions (vectorized float4 loads).
//   ft[z,j]   = sum_{c,d} f[z,c,d,j]
//   Gs[z,x,j] = sum_{c,d} geom[z,c,x] * f[z,c,d,j]
//   Gd[z,x,j] = sum_{c,d} geom[z,d,x] * f[z,c,d,j]
// 64 blocks (32 slices per z), 256 threads = 32 row-groups x 8 col-groups.
// Each row-group covers 4 (c,d) pairs; each col-group covers 4 j channels.
// Block writes one partial slice [7][32].
// ---------------------------------------------------------------------------
__global__ __launch_bounds__(256) void k_reduce(const float* __restrict__ feat,
                                                const float* __restrict__ geom,
                                                float* __restrict__ part) {
    const int bid = blockIdx.x;
    const int z = bid >> 5;        // 0..1
    const int s = bid & 31;        // slice 0..31
    const int tid = threadIdx.x;
    const int cg = tid & 7;        // j0 = cg*4
    const int rg = tid >> 3;       // 0..31

    __shared__ float gsh[NN * 3];
    __shared__ float red[32][7][32];   // 28 KB

    if (tid < NN * 3) gsh[tid] = geom[z * NN * 3 + tid];
    __syncthreads();

    float ft[4] = {0.f, 0.f, 0.f, 0.f};
    float As[3][4] = {{0.f}};   // Gs partials (x, jk)
    float Ad[3][4] = {{0.f}};   // Gd partials

    const float* fz = feat + (size_t)z * NN * NN * NCI;
    const int p0 = s * 128 + rg * 4;
    #pragma unroll
    for (int t = 0; t < 4; ++t) {
        const int p = p0 + t;
        float f[4];
        ld4(fz + (size_t)p * NCI + cg * 4, f);
        const int c = p >> 6;
        const int d = p & 63;
        float gc[3], gd[3];
        #pragma unroll
        for (int x = 0; x < 3; ++x) { gc[x] = gsh[c * 3 + x]; gd[x] = gsh[d * 3 + x]; }
        #pragma unroll
        for (int k = 0; k < 4; ++k) {
            ft[k] += f[k];
            #pragma unroll
            for (int x = 0; x < 3; ++x) {
                As[x][k] = fmaf(gc[x], f[k], As[x][k]);
                Ad[x][k] = fmaf(gd[x], f[k], Ad[x][k]);
            }
        }
    }

    const int j0 = cg * 4;
    #pragma unroll
    for (int k = 0; k < 4; ++k) {
        red[rg][0][j0 + k] = ft[k];
        #pragma unroll
        for (int x = 0; x < 3; ++x) {
            red[rg][1 + x][j0 + k] = As[x][k];
            red[rg][4 + x][j0 + k] = Ad[x][k];
        }
    }
    __syncthreads();

    if (tid < 7 * 32) {
        const int q = tid >> 5, jj = tid & 31;
        float sum = 0.f;
        #pragma unroll
        for (int g = 0; g < 32; ++g) sum += red[g][q][jj];
        part[(size_t)z * PART_Z_STRIDE + (s * 7 + q) * 32 + jj] = sum;
    }
}

// ---------------------------------------------------------------------------
// Kernel 2 (fused coeff + output): each block redundantly finishes the
// reduction and folds W into per-z tables (all L2-resident), then writes its
// 1024-element output chunk.
//   Qm[z,x,i]  = sum_j Wm[x,i,j] * ft[z,j]
//   QA = scale*(Q1+Q2+Q3)  (multiplies -g_a[x]);  QB = scale*(Q1-Q4-Q5)  (+g_b[x])
//   gamma[z,i] = scale * sum_{x,j} [(W2+W4-W6)*Gs + (W3+W5+W6)*Gd]
//   out[z,a,b,i] = gamma + sum_x (g_b[x]*QB[x,i] - g_a[x]*QA[x,i])
// 256 blocks (128 per z), 256 threads, one float4 store per thread.
// ---------------------------------------------------------------------------
__global__ __launch_bounds__(256) void k_out(const float* __restrict__ part,
                                             const float* __restrict__ W,
                                             const float* __restrict__ geom,
                                             const int* __restrict__ nnp,
                                             float* __restrict__ out) {
    const int z = blockIdx.x >> 7;
    const int tid = threadIdx.x;

    __shared__ float gsh[NN * 3];
    __shared__ float acc[7][32];            // ft, Gs[0..2], Gd[0..2]
    __shared__ float sQA[3][32], sQB[3][32], gred[3][32], sgam[32];

    if (tid < NN * 3) gsh[tid] = geom[z * NN * 3 + tid];

    // Phase 1: finish the partial-slice reduction (32 slices).
    if (tid < 7 * 32) {
        const int q = tid >> 5, j = tid & 31;
        const float* pz = part + (size_t)z * PART_Z_STRIDE;
        float sum = 0.f;
        #pragma unroll 8
        for (int sl = 0; sl < 32; ++sl) sum += pz[(sl * 7 + q) * 32 + j];
        acc[q][j] = sum;
    }
    __syncthreads();

    // n_norm: Python scalar -> 1-elem array; hedge int32 vs float32 bits.
    const int v = *nnp;
    const float nn = (v > 0 && v < (1 << 23)) ? (float)v : __int_as_float(v);
    const float scale = 1.0f / sqrtf(6.0f * nn * nn);

    // Phase 2: fold W into QA/QB/gamma tables.
    if (tid < 96) {
        const int x = tid >> 5;    // 0..2
        const int i = tid & 31;
        const float* Wp = W + x * 6 * NCO * NCI + i * NCI;   // rows m*1024 apart
        float q1 = 0.f, q23 = 0.f, q45 = 0.f, gp = 0.f;
        #pragma unroll 2
        for (int j4 = 0; j4 < 8; ++j4) {
            float w[6][4];
            #pragma unroll
            for (int m = 0; m < 6; ++m) ld4(Wp + m * 1024 + j4 * 4, w[m]);
            #pragma unroll
            for (int k = 0; k < 4; ++k) {
                const int j = j4 * 4 + k;
                const float ftj = acc[0][j];
                const float gsj = acc[1 + x][j];
                const float gdj = acc[4 + x][j];
                q1  = fmaf(w[0][k], ftj, q1);
                q23 = fmaf(w[1][k] + w[2][k], ftj, q23);
                q45 = fmaf(w[3][k] + w[4][k], ftj, q45);
                gp  = fmaf(w[1][k] + w[3][k] - w[5][k], gsj, gp);
                gp  = fmaf(w[2][k] + w[4][k] + w[5][k], gdj, gp);
            }
        }
        sQA[x][i] = scale * (q1 + q23);
        sQB[x][i] = scale * (q1 - q45);
        gred[x][i] = gp;
    }
    __syncthreads();
    if (tid < 32) sgam[tid] = scale * (gred[0][tid] + gred[1][tid] + gred[2][tid]);
    __syncthreads();

    // Phase 3: write this block's 1024-element output chunk.
    const int i0 = (tid & 7) * 4;                       // channel group
    const int ab = ((blockIdx.x & 127) << 5) + (tid >> 3);  // 0..4095
    const int a = ab >> 6, b = ab & 63;

    float r[4];
    #pragma unroll
    for (int k = 0; k < 4; ++k) r[k] = sgam[i0 + k];
    #pragma unroll
    for (int x = 0; x < 3; ++x) {
        const float gb = gsh[b * 3 + x];
        const float ga = gsh[a * 3 + x];
        #pragma unroll
        for (int k = 0; k < 4; ++k) {
            r[k] = fmaf(gb, sQB[x][i0 + k], r[k]);
            r[k] = fmaf(-ga, sQA[x][i0 + k], r[k]);
        }
    }
    float4 o; o.x = r[0]; o.y = r[1]; o.z = r[2]; o.w = r[3];
    *(float4*)(out + ((size_t)(z * 4096 + ab)) * 32 + i0) = o;
}

extern "C" void kernel_launch(void* const* d_in, const int* in_sizes, int n_in,
                              void* d_out, int out_size, void* d_ws, size_t ws_size,
                              hipStream_t stream) {
    const float* feat = (const float*)d_in[0];   // [2,64,64,32]
    const float* geom = (const float*)d_in[1];   // [2,64,3]
    const float* W    = (const float*)d_in[2];   // [3,6144]
    const int*   nnp  = (const int*)d_in[3];     // scalar n_norm

    float* part = (float*)d_ws;                  // [2][32][7][32]
    float* out  = (float*)d_out;

    k_reduce<<<NZ * 32, 256, 0, stream>>>(feat, geom, part);
    k_out<<<NZ * 128, 256, 0, stream>>>(part, W, geom, nnp, out);
}